// Round 6
// baseline (933.491 us; speedup 1.0000x reference)
//
#include <hip/hip_runtime.h>
#include <hip/hip_bf16.h>
#include <stdint.h>

// EncoderLayer: B=4 S=4096 D=1024 H=16 HD=64 HL=8 STRIDE=128 C=32 DFF=4096
// bf16 MFMA internal compute (validated: absmax 0.031 vs 0.109 threshold).
// R12: sched_group_barrier interleave in gemm_bt. R10 (no fence) sank all
// next-tile ds_reads below the MFMAs; R11 (trailing sched_barrier) pinned
// them all above, in a SEPARATE region -- both phase-serialized (all 8 waves
// flood LDS ~1150cyc with matrix pipe idle, then MFMA ~1024cyc with LDS
// idle; 3800cyc/window measured, MfmaUtil 29% = 1024/3800). Fix: ONE region
// per window (keep the post-barrier fence for the cross-wave staging race,
// drop the trailing fence) + T19 directive run 4x{3 DS_READ, 1 VMEM, 8 MFMA}
// so each wave's stream interleaves reads under MFMAs. setprio dropped in
// gemm (may split the scheduling region; null for 2ph GEMM per m190).

typedef unsigned short bf16_t;
typedef __attribute__((ext_vector_type(8))) short short8;
typedef __attribute__((ext_vector_type(4))) float v4f;

static __device__ __forceinline__ unsigned short f2b(float f) {
    unsigned int x = __float_as_uint(f);
    x += 0x7fffu + ((x >> 16) & 1u);   // RNE
    return (unsigned short)(x >> 16);
}
static __device__ __forceinline__ float b2f(unsigned short u) {
    return __uint_as_float(((unsigned int)u) << 16);
}

// async global->LDS 16B: LDS dest is wave-uniform base + lane*16
static __device__ __forceinline__ void gload16(const void* g, void* l) {
    __builtin_amdgcn_global_load_lds(
        (const __attribute__((address_space(1))) uint32_t*)g,
        (__attribute__((address_space(3))) uint32_t*)l, 16, 0, 0);
}

template<int N>
static __device__ __forceinline__ void vmwait() {
    asm volatile("s_waitcnt vmcnt(%0)" :: "n"(N) : "memory");
}
static __device__ __forceinline__ void lgkmwait0() {
    asm volatile("s_waitcnt lgkmcnt(0)" ::: "memory");
}

// ---------------- converts ----------------

__global__ __launch_bounds__(256) void transpose_convert(
    const float* __restrict__ W, bf16_t* __restrict__ Wt, int K, int N) {
    __shared__ float tile[32][33];
    int n0 = blockIdx.x * 32, k0 = blockIdx.y * 32;
    int tx = threadIdx.x, ty = threadIdx.y;
    for (int i = ty; i < 32; i += 8)
        tile[i][tx] = W[(size_t)(k0 + i) * N + n0 + tx];
    __syncthreads();
    for (int i = ty; i < 32; i += 8)
        Wt[(size_t)(n0 + i) * K + k0 + tx] = f2b(tile[tx][i]);
}

__global__ __launch_bounds__(256) void f32_to_bf16_vec(
    const float* __restrict__ in, bf16_t* __restrict__ out, int n4) {
    int i = blockIdx.x * blockDim.x + threadIdx.x;
    if (i >= n4) return;
    float4 v = ((const float4*)in)[i];
    uint2 p;
    p.x = (unsigned)f2b(v.x) | ((unsigned)f2b(v.y) << 16);
    p.y = (unsigned)f2b(v.z) | ((unsigned)f2b(v.w) << 16);
    ((uint2*)out)[i] = p;
}

// ---------------- V transpose prepass ----------------
// Builds vt[(b*8+h)*64 + d][tok'] (bf16) from qkv's V segment, where tok' is
// the compacted key index (identity for local heads, the C=32 tail-of-stride
// gather for global heads). XOR-swizzled LDS tile (row>>3) keeps both phases
// bank-conflict-free at short8 width.
template<bool GLOBAL>
__global__ __launch_bounds__(256) void v_transpose(
    const bf16_t* __restrict__ qkv, bf16_t* __restrict__ vt, int ntok) {
    __shared__ bf16_t tile[4096];
    int tb = blockIdx.x, h = blockIdx.y, b = blockIdx.z;
    int t = threadIdx.x;
    size_t src = (size_t)b * 4096 * 3072 + (size_t)(GLOBAL ? h + 8 : h) * 64 + 2048;
    for (int u = t; u < 512; u += 256) {
        int row = u >> 3, g = u & 7;
        int lt = tb * 64 + row;
        int tok = GLOBAL ? ((lt >> 5) * 128 + 96 + (lt & 31)) : lt;
        short8 vrow = *(const short8*)(qkv + src + (size_t)tok * 3072 + g * 8);
        *(short8*)&tile[(row * 8 + (g ^ (row >> 3))) * 8] = vrow;
    }
    __syncthreads();
    for (int u = t; u < 512; u += 256) {
        int d = u >> 3, t8g = u & 7;
        short8 vcol;
#pragma unroll
        for (int j = 0; j < 8; ++j) {
            int row = t8g * 8 + j;
            vcol[j] = tile[(row * 8 + ((d >> 3) ^ (row >> 3))) * 8 + (d & 7)];
        }
        *(short8*)(vt + ((size_t)(b * 8 + h) * 64 + d) * ntok + (size_t)tb * 64 + t8g * 8) = vcol;
    }
}

// ---------------- GEMM: C[M][N] = A[M][K] @ Bt[N][K]^T + bias (+res)(+relu) ---------
// BM=256 fixed, BN template (only 256 instantiated). BK=32. 512 threads =
// 8 waves (2 M x 4 N). 4 circular LDS K-tile buffers, counted vmcnt, raw
// s_barrier + post-barrier fence, reg double-buffered fragments, and an
// SGB-driven interleave of {next-tile ds_reads, stage, current MFMAs}.
template<int BN>
__global__ __launch_bounds__(512, 2) void gemm_bt(
    const bf16_t* __restrict__ A, const bf16_t* __restrict__ Bt,
    const float* __restrict__ bias, const float* __restrict__ bias2,
    const float* __restrict__ bias3, const float* __restrict__ resf,
    const bf16_t* __restrict__ resb, float* __restrict__ Cf,
    bf16_t* __restrict__ Cb, int N, int K, int relu) {
    constexpr int N_REP = BN / 64;     // fB frags per wave
    constexpr int BLD = BN / 128;      // B staging passes (512 units each)
    constexpr int LPT = 2 + BLD;       // gload16 per thread per K-tile
    constexpr int ASH = 8192;          // A-tile shorts (256x32)
    constexpr int TSH = ASH + BN * 32; // shorts per buffer
    __shared__ bf16_t lds[4][TSH];

    int t = threadIdx.x;
    int lane = t & 63;
    int wave = t >> 6;
    int wm = (wave >> 2) * 128;
    int wn = (wave & 3) * (BN / 4);
    int m0 = blockIdx.x * 256, n0 = blockIdx.y * BN;

    size_t aoff[2]; int adst[2];
#pragma unroll
    for (int p = 0; p < 2; ++p) {
        int u = p * 512 + t;
        int row = ((u >> 6) << 4) + (lane & 15);
        int kk = ((u >> 4) & 3) * 8;
        aoff[p] = (size_t)(m0 + row) * K + kk;
        adst[p] = (u & ~63) * 8;
    }
    size_t boff[BLD]; int bdst[BLD];
#pragma unroll
    for (int p = 0; p < BLD; ++p) {
        int u = p * 512 + t;
        int row = ((u >> 6) << 4) + (lane & 15);
        int kk = ((u >> 4) & 3) * 8;
        boff[p] = (size_t)(n0 + row) * K + kk;
        bdst[p] = (u & ~63) * 8;
    }

    auto stage = [&](int buf, int kt) {
        int k0 = kt * 32;
#pragma unroll
        for (int p = 0; p < 2; ++p)
            gload16(A + aoff[p] + k0, &lds[buf][adst[p]]);
#pragma unroll
        for (int p = 0; p < BLD; ++p)
            gload16(Bt + boff[p] + k0, &lds[buf][ASH + bdst[p]]);
    };

    v4f acc[8][N_REP];
#pragma unroll
    for (int i = 0; i < 8; ++i)
#pragma unroll
        for (int j = 0; j < N_REP; ++j) acc[i][j] = {0.f, 0.f, 0.f, 0.f};

    int NT = K >> 5;
    stage(0, 0); stage(1, 1); stage(2, 2);

    int aro = (wm >> 4) * 512 + lane * 8;
    int bro = ASH + (wn >> 4) * 512 + lane * 8;

    short8 fA0[8], fB0[N_REP], fA1[8], fB1[N_REP];

    // prologue: tile 0 -> set0
    vmwait<2 * LPT>();
    __builtin_amdgcn_s_barrier();
    __builtin_amdgcn_sched_barrier(0);
#pragma unroll
    for (int i = 0; i < 8; ++i) fA0[i] = *(const short8*)&lds[0][aro + i * 512];
#pragma unroll
    for (int j = 0; j < N_REP; ++j) fB0[j] = *(const short8*)&lds[0][bro + j * 512];

    // window(it): [vmcnt(counted); s_barrier; fence] then ONE scheduling
    // region containing: 12 ds_reads (tile it+1 -> rA/rB), LPT gload_lds
    // (tile it+3), 32 MFMA (tile it from mA/mB). The SGB run interleaves
    // them 3:1:8 x4 so the LDS stream hides under the MFMA cluster.
    // Safety identical to R11: post-barrier fence stops cross-barrier
    // hoisting (cross-wave staging race); stage target buf[(it+3)&3] ==
    // buf[(it-1)&3], readers done >=2 barriers ago; vmwait<LPT> = own
    // tile-(it+1) loads landed (issued 2 windows ago), barrier makes it
    // collective.
    auto window = [&](int it, short8 (&rA)[8], short8 (&rB)[N_REP],
                      short8 (&mA)[8], short8 (&mB)[N_REP]) {
        bool head = (it + 1 < NT);
        if (head) {
            if (it + 2 < NT) vmwait<LPT>();
            else vmwait<0>();
            __builtin_amdgcn_s_barrier();
            __builtin_amdgcn_sched_barrier(0);
            int nb = (it + 1) & 3;
#pragma unroll
            for (int i = 0; i < 8; ++i)
                rA[i] = *(const short8*)&lds[nb][aro + i * 512];
#pragma unroll
            for (int j = 0; j < N_REP; ++j)
                rB[j] = *(const short8*)&lds[nb][bro + j * 512];
            if (it + 3 < NT) stage((it + 3) & 3, it + 3);
        }
#pragma unroll
        for (int i = 0; i < 8; ++i)
#pragma unroll
            for (int j = 0; j < N_REP; ++j)
                acc[i][j] = __builtin_amdgcn_mfma_f32_16x16x32_bf16(mA[i], mB[j], acc[i][j], 0, 0, 0);
        if (head) {
            // T19 interleave directive run (one scheduling region):
            // totals DS_READ=8+N_REP, VMEM=LPT, MFMA=8*N_REP.
#pragma unroll
            for (int g = 0; g < 4; ++g) {
                __builtin_amdgcn_sched_group_barrier(0x100, (8 + N_REP) / 4, 0); // DS_READ
                __builtin_amdgcn_sched_group_barrier(0x030, 1, 0);               // VMEM (gload_lds)
                __builtin_amdgcn_sched_group_barrier(0x008, 2 * N_REP, 0);       // MFMA
            }
        }
    };

    // NT is even for all instances (32 or 128): hand-2-stepped loop keeps
    // fragment sets statically named (rule: no runtime-indexed reg arrays).
    for (int it = 0; it < NT; it += 2) {
        window(it,     fA1, fB1, fA0, fB0);   // read it+1, MFMA it
        window(it + 1, fA0, fB0, fA1, fB1);   // read it+2, MFMA it+1
    }

    int qrow = (lane >> 4) * 4;
    int c15 = lane & 15;
#pragma unroll
    for (int i = 0; i < 8; ++i) {
#pragma unroll
        for (int j = 0; j < N_REP; ++j) {
            int col = n0 + wn + j * 16 + c15;
            float bval;
            if (bias2) {
                int seg = col >> 10;
                const float* bp = seg == 0 ? bias : (seg == 1 ? bias2 : bias3);
                bval = bp[col & 1023];
            } else {
                bval = bias[col];
            }
#pragma unroll
            for (int r = 0; r < 4; ++r) {
                int row = m0 + wm + i * 16 + qrow + r;
                size_t idx = (size_t)row * N + col;
                float val = acc[i][j][r] + bval;
                if (resf) val += resf[idx];
                if (resb) val += b2f(resb[idx]);
                if (relu) val = fmaxf(val, 0.f);
                if (Cf) Cf[idx] = val;
                if (Cb) Cb[idx] = f2b(val);
            }
        }
    }
}

// ---------------- MFMA flash attention, pipelined (R8) ----------------
// qkv interleaved [tok][3072]: q +0, k +1024, v +2048. vt is the prepass
// output [bh*64+d][tok'] (compacted keys). NCHUNK counts 64-key chunks.
// LDS (shorts): [0,8192) Q (preload) aliased by P (128q x 64k A-frag);
//   [8192,20480) K bufs 3 x 4096; [20480,32768) Vt bufs 3 x 4096. 64KB.
template<int NCHUNK, bool GLOBAL>
__global__ __launch_bounds__(256) void mfma_attn(
    const bf16_t* __restrict__ qkv, const bf16_t* __restrict__ vt,
    bf16_t* __restrict__ o, int head_base) {
    __shared__ bf16_t buf[32768];
    bf16_t* ldsQ = buf;
    bf16_t* ldsP = buf;
    constexpr int KB = 8192, VB = 20480;

    int qc = blockIdx.x, hh = blockIdx.y, b = blockIdx.z;
    int h = head_base + hh;
    int t = threadIdx.x, lane = t & 63, w = t >> 6;
    int quad = lane >> 4, c15 = lane & 15;
    size_t base = (size_t)b * 4096 * 3072 + (size_t)h * 64;
    const int NTOK = GLOBAL ? 1024 : 4096;
    size_t vtbase = (size_t)(b * 8 + hh) * 64 * NTOK + (GLOBAL ? 0 : (size_t)qc * 128);
    const int CADV = (GLOBAL ? 256 : 64) * 3072;   // K token advance per chunk

    size_t koff[2]; int kdst[2];
#pragma unroll
    for (int p = 0; p < 2; ++p) {
        int u = p * 256 + t;
        int s = u >> 8;
        int kl = ((u >> 6) & 3) * 16 + (lane & 15);
        int dk = s * 32 + ((lane >> 4) & 3) * 8;
        int tok0 = GLOBAL ? ((kl >> 5) * 128 + 96 + (kl & 31)) : (qc * 128 + kl);
        koff[p] = base + 1024 + (size_t)tok0 * 3072 + dk;
        kdst[p] = KB + (u & ~63) * 8;
    }
    size_t voff[2]; int vdst[2];
#pragma unroll
    for (int p = 0; p < 2; ++p) {
        int u = p * 256 + t;
        int dd = ((u >> 6) & 3) * 16 + (lane & 15);
        int kl = (u >> 8) * 32 + ((lane >> 4) & 3) * 8;
        voff[p] = vtbase + (size_t)dd * NTOK + kl;
        vdst[p] = VB + (u & ~63) * 8;
    }

    auto stage = [&](int c) {
        int q = c % 3;
        size_t ka = (size_t)c * CADV;
        size_t va = (size_t)c * 64;
#pragma unroll
        for (int p = 0; p < 2; ++p)
            gload16(qkv + koff[p] + ka, buf + kdst[p] + q * 4096);
#pragma unroll
        for (int p = 0; p < 2; ++p)
            gload16(vt + voff[p] + va, buf + vdst[p] + q * 4096);
    };

    // ---- stage Q in A-frag order ----
#pragma unroll
    for (int u = t; u < 1024; u += 256) {
        int s = u >> 9, mt = (u >> 6) & 7, qq = (u >> 4) & 3, ll = u & 15;
        int tok = qc * 128 + mt * 16 + ll;
        gload16(qkv + base + (size_t)tok * 3072 + s * 32 + qq * 8, ldsQ + (u & ~63) * 8);
    }
    stage(0);
    stage(1);
    vmwait<8>();                       // Q's 4 loads (oldest) landed, all waves
    __builtin_amdgcn_s_barrier();

    short8 fQ[2][2];
#pragma unroll
    for (int i = 0; i < 2; ++i)
#pragma unroll
        for (int s = 0; s < 2; ++s)
            fQ[i][s] = *(const short8*)(ldsQ + (s * 512 + (w * 2 + i) * 64 + lane) * 8);
    lgkmwait0();                       // fQ in regs before P region gets written
    __builtin_amdgcn_sched_barrier(0);

    v4f oacc[2][4];
    float lacc[2][4];
#pragma unroll
    for (int i = 0; i < 2; ++i)
#pragma unroll
        for (int n = 0; n < 4; ++n) oacc[i][n] = {0.f, 0.f, 0.f, 0.f};
#pragma unroll
    for (int i = 0; i < 2; ++i)
#pragma unroll
        for (int r = 0; r < 4; ++r) lacc[i][r] = 0.f;

    for (int c = 0; c < NCHUNK; ++c) {
        if (c + 1 < NCHUNK) vmwait<4>();
        else vmwait<0>();
        __builtin_amdgcn_s_barrier();
        __builtin_amdgcn_sched_barrier(0);
        if (c + 2 < NCHUNK) stage(c + 2);

        const bf16_t* Kq = buf + KB + (c % 3) * 4096;
        const bf16_t* Vq = buf + VB + (c % 3) * 4096;

        // ---- S = Q K^T ----
        v4f sacc[2][4];
#pragma unroll
        for (int i = 0; i < 2; ++i)
#pragma unroll
            for (int j = 0; j < 4; ++j) sacc[i][j] = {0.f, 0.f, 0.f, 0.f};
        __builtin_amdgcn_s_setprio(1);
#pragma unroll
        for (int s = 0; s < 2; ++s)
#pragma unroll
            for (int j = 0; j < 4; ++j) {
                short8 fK = *(const short8*)(Kq + (s * 256 + j * 64 + lane) * 8);
#pragma unroll
                for (int i = 0; i < 2; ++i)
                    sacc[i][j] = __builtin_amdgcn_mfma_f32_16x16x32_bf16(fQ[i][s], fK, sacc[i][j], 0, 0, 0);
            }
        __builtin_amdgcn_s_setprio(0);

        // ---- P = exp(S*scale); l += rowsum; P -> ldsP (A-frag, swizzled) ----
#pragma unroll
        for (int i = 0; i < 2; ++i) {
            float rs[4] = {0.f, 0.f, 0.f, 0.f};
#pragma unroll
            for (int j = 0; j < 4; ++j)
#pragma unroll
                for (int r = 0; r < 4; ++r) {
                    float p = __expf(sacc[i][j][r] * 0.125f);
                    sacc[i][j][r] = p;
                    rs[r] += p;
                }
#pragma unroll
            for (int m = 1; m < 16; m <<= 1)
#pragma unroll
                for (int r = 0; r < 4; ++r) rs[r] += __shfl_xor(rs[r], m);
#pragma unroll
            for (int r = 0; r < 4; ++r) lacc[i][r] += rs[r];
#pragma unroll
            for (int j = 0; j < 4; ++j) {
                int tt = j >> 1;
                int qq = (2 * j + (c15 >> 3)) & 3;
#pragma unroll
                for (int r = 0; r < 4; ++r) {
                    int slot = (quad * 4 + r) ^ qq;
                    int unit = (w * 2 + tt) * 128 + i * 64 + qq * 16 + slot;
                    ldsP[unit * 8 + (c15 & 7)] = f2b(sacc[i][j][r]);
                }
            }
        }

        // ---- O += P V (per-wave ldsP region: no barrier needed) ----
        __builtin_amdgcn_s_setprio(1);
#pragma unroll
        for (int tt = 0; tt < 2; ++tt) {
            short8 fP[2];
#pragma unroll
            for (int i = 0; i < 2; ++i)
                fP[i] = *(const short8*)(ldsP + ((w * 2 + tt) * 128 + i * 64
                              + quad * 16 + (c15 ^ quad)) * 8);
#pragma unroll
            for (int n = 0; n < 4; ++n) {
                short8 fV = *(const short8*)(Vq + (tt * 256 + n * 64 + lane) * 8);
#pragma unroll
                for (int i = 0; i < 2; ++i)
                    oacc[i][n] = __builtin_amdgcn_mfma_f32_16x16x32_bf16(fP[i], fV, oacc[i][n], 0, 0, 0);
            }
        }
        __builtin_amdgcn_s_setprio(0);
    }

    // ---- epilogue: O / l ----
#pragma unroll
    for (int i = 0; i < 2; ++i)
#pragma unroll
        for (int r = 0; r < 4; ++r) {
            int row = qc * 128 + (w * 2 + i) * 16 + quad * 4 + r;
            float inv = 1.f / lacc[i][r];
            bf16_t* orow = o + ((size_t)b * 4096 + row) * 1024 + h * 64;
#pragma unroll
            for (int n = 0; n < 4; ++n)
                orow[n * 16 + c15] = f2b(oacc[i][n][r] * inv);
        }
}

// ---------------- layernorm (may run in-place) ----------------
__global__ __launch_bounds__(256) void ln_kernel(
    const float* x, const float* g, const float* bta,
    float* outf, bf16_t* outb) {
    int row = blockIdx.x, t = threadIdx.x;
    const float4 vv = ((const float4*)(x + (size_t)row * 1024))[t];
    float s = vv.x + vv.y + vv.z + vv.w;
    float ss = vv.x * vv.x + vv.y * vv.y + vv.z * vv.z + vv.w * vv.w;
    for (int off = 32; off > 0; off >>= 1) {
        s += __shfl_down(s, off);
        ss += __shfl_down(ss, off);
    }
    __shared__ float red[8];
    int wave = t >> 6;
    if ((t & 63) == 0) { red[wave] = s; red[wave + 4] = ss; }
    __syncthreads();
    float ts = red[0] + red[1] + red[2] + red[3];
    float tss = red[4] + red[5] + red[6] + red[7];
    float mu = ts * (1.f / 1024.f);
    float var = tss * (1.f / 1024.f) - mu * mu;
    float rstd = rsqrtf(var + 1e-6f);
    float4 gv = ((const float4*)g)[t];
    float4 bv = ((const float4*)bta)[t];
    float4 ov;
    ov.x = (vv.x - mu) * rstd * gv.x + bv.x;
    ov.y = (vv.y - mu) * rstd * gv.y + bv.y;
    ov.z = (vv.z - mu) * rstd * gv.z + bv.z;
    ov.w = (vv.w - mu) * rstd * gv.w + bv.w;
    if (outf) ((float4*)(outf + (size_t)row * 1024))[t] = ov;
    if (outb) {
        uint2 pk;
        pk.x = (unsigned)f2b(ov.x) | ((unsigned)f2b(ov.y) << 16);
        pk.y = (unsigned)f2b(ov.z) | ((unsigned)f2b(ov.w) << 16);
        ((uint2*)(outb + (size_t)row * 1024))[t] = pk;
    }
}

// ---------------- launch ----------------
extern "C" void kernel_launch(void* const* d_in, const int* in_sizes, int n_in,
                              void* d_out, int out_size, void* d_ws, size_t ws_size,
                              hipStream_t stream) {
    const float* src = (const float*)d_in[0];
    const float* Wq = (const float*)d_in[2];  const float* bq = (const float*)d_in[3];
    const float* Wk = (const float*)d_in[4];  const float* bk = (const float*)d_in[5];
    const float* Wv = (const float*)d_in[6];  const float* bv = (const float*)d_in[7];
    const float* Wo = (const float*)d_in[8];  const float* bo = (const float*)d_in[9];
    const float* g1 = (const float*)d_in[10]; const float* be1 = (const float*)d_in[11];
    const float* W1 = (const float*)d_in[12]; const float* b1 = (const float*)d_in[13];
    const float* W2 = (const float*)d_in[14]; const float* b2 = (const float*)d_in[15];
    const float* g2 = (const float*)d_in[16]; const float* be2 = (const float*)d_in[17];
    float* out = (float*)d_out;   // also the fp32 residual stream (64 MB)
    char* ws = (char*)d_ws;
    const size_t MB = 1ull << 20;

    // layout (MB), ws >= 176 confirmed r5. Lifetimes:
    //  [0,32)    xb -> ob -> alnb          (sequential)
    //  [32,128)  qkv (96)                  (dead after attn)
    //  [128,144) vt_l  [144,148) vt_g      (dead after attn)
    //  [152,158) wqkvt (dead after QKV)  [158,160) wot (dead after out-proj)
    //  [160,168) w1t  [168,176) w2t        (live through FFN)
    //  hb = [32,160) 128MB                 (written by FFN1, after all above die)
    bf16_t* xb    = (bf16_t*)(ws + 0 * MB);
    bf16_t* ob    = (bf16_t*)(ws + 0 * MB);
    bf16_t* alnb  = (bf16_t*)(ws + 0 * MB);
    bf16_t* qkv   = (bf16_t*)(ws + 32 * MB);
    bf16_t* hb    = (bf16_t*)(ws + 32 * MB);
    bf16_t* vt_l  = (bf16_t*)(ws + 128 * MB);
    bf16_t* vt_g  = (bf16_t*)(ws + 144 * MB);
    bf16_t* wqkvt = (bf16_t*)(ws + 152 * MB);
    bf16_t* wot   = (bf16_t*)(ws + 158 * MB);
    bf16_t* w1t   = (bf16_t*)(ws + 160 * MB);
    bf16_t* w2t   = (bf16_t*)(ws + 168 * MB);

    dim3 tb(32, 8);
    transpose_convert<<<dim3(32, 32), tb, 0, stream>>>(Wq, wqkvt, 1024, 1024);
    transpose_convert<<<dim3(32, 32), tb, 0, stream>>>(Wk, wqkvt + 1024 * 1024, 1024, 1024);
    transpose_convert<<<dim3(32, 32), tb, 0, stream>>>(Wv, wqkvt + 2 * 1024 * 1024, 1024, 1024);
    transpose_convert<<<dim3(32, 32), tb, 0, stream>>>(Wo, wot, 1024, 1024);
    transpose_convert<<<dim3(128, 32), tb, 0, stream>>>(W1, w1t, 1024, 4096);
    transpose_convert<<<dim3(32, 128), tb, 0, stream>>>(W2, w2t, 4096, 1024);
    f32_to_bf16_vec<<<16384, 256, 0, stream>>>(src, xb, 4194304);

    // fused QKV: C[M][3072] = xb @ [Wq|Wk|Wv]^T, per-segment bias
    gemm_bt<256><<<dim3(64, 12), 512, 0, stream>>>(xb, wqkvt, bq, bk, bv,
        nullptr, nullptr, nullptr, qkv, 3072, 1024, 0);

    // V transpose prepass (local heads 0..8 over all toks; global heads 8..16
    // over the 1024 compacted keys)
    v_transpose<false><<<dim3(64, 8, 4), 256, 0, stream>>>(qkv, vt_l, 4096);
    v_transpose<true ><<<dim3(16, 8, 4), 256, 0, stream>>>(qkv, vt_g, 1024);

    mfma_attn<2,  false><<<dim3(32, 8, 4), 256, 0, stream>>>(qkv, vt_l, ob, 0);
    mfma_attn<16, true ><<<dim3(32, 8, 4), 256, 0, stream>>>(qkv, vt_g, ob, 8);

    // out-proj + src residual -> out (fp32)
    gemm_bt<256><<<dim3(64, 4), 512, 0, stream>>>(ob, wot, bo, nullptr, nullptr,
        src, nullptr, out, nullptr, 1024, 1024, 0);
    ln_kernel<<<16384, 256, 0, stream>>>(out, g1, be1, nullptr, alnb);

    // FFN unchunked: hb spans [32,160) (qkv/vt/wqkvt/wot all dead by now).
    // FFN1: M=16384 N=4096 (grid 1024 = 4 full passes). FFN2: BN=256,
    // grid 64x4 = 256 blocks = exactly 1 pass.
    gemm_bt<256><<<dim3(64, 16), 512, 0, stream>>>(alnb, w1t, b1, nullptr, nullptr,
        nullptr, nullptr, nullptr, hb, 4096, 1024, 1);
    gemm_bt<256><<<dim3(64, 4), 512, 0, stream>>>(hb, w2t, b2, nullptr, nullptr,
        nullptr, alnb, out, nullptr, 1024, 4096, 0);
    ln_kernel<<<16384, 256, 0, stream>>>(out, g2, be2, out, nullptr);

    (void)in_sizes; (void)n_in; (void)out_size; (void)ws_size;
}

// Round 7
// 922.026 us; speedup vs baseline: 1.0124x; 1.0124x over previous
//
#include <hip/hip_runtime.h>
#include <hip/hip_bf16.h>
#include <stdint.h>

// EncoderLayer: B=4 S=4096 D=1024 H=16 HD=64 HL=8 STRIDE=128 C=32 DFF=4096
// bf16 MFMA internal compute (validated: absmax 0.031 vs 0.109 threshold).
// R13: gemm K-loop ported to the proven 8-phase/256^2 structure (m201/m248):
// BK=64, 2 LDS buffers (A 32KB + B 32KB each, staged as k-halves), 4 phases
// per K-tile: {ds_reads + 1 half-stage -> barrier -> lgkm(0) -> 16 MFMA ->
// barrier}, counted vmwait<4> before the CLOSING barrier of odd phases
// (one barrier ahead of dependent reads -> collective), never 0 in-loop.
// Body is branch-free (stage clamps kt=min(t+1,NT-1)); R10-R12's three
// scheduling nulls were root-caused to runtime-NT control flow splitting
// the scheduling region -- this structure has none.
// Attn (R8), v_transpose, LN, FFN layout (R11) unchanged.

typedef unsigned short bf16_t;
typedef __attribute__((ext_vector_type(8))) short short8;
typedef __attribute__((ext_vector_type(4))) float v4f;

static __device__ __forceinline__ unsigned short f2b(float f) {
    unsigned int x = __float_as_uint(f);
    x += 0x7fffu + ((x >> 16) & 1u);   // RNE
    return (unsigned short)(x >> 16);
}
static __device__ __forceinline__ float b2f(unsigned short u) {
    return __uint_as_float(((unsigned int)u) << 16);
}

// async global->LDS 16B: LDS dest is wave-uniform base + lane*16
static __device__ __forceinline__ void gload16(const void* g, void* l) {
    __builtin_amdgcn_global_load_lds(
        (const __attribute__((address_space(1))) uint32_t*)g,
        (__attribute__((address_space(3))) uint32_t*)l, 16, 0, 0);
}

template<int N>
static __device__ __forceinline__ void vmwait() {
    asm volatile("s_waitcnt vmcnt(%0)" :: "n"(N) : "memory");
}
static __device__ __forceinline__ void lgkmwait0() {
    asm volatile("s_waitcnt lgkmcnt(0)" ::: "memory");
}

// ---------------- converts ----------------

__global__ __launch_bounds__(256) void transpose_convert(
    const float* __restrict__ W, bf16_t* __restrict__ Wt, int K, int N) {
    __shared__ float tile[32][33];
    int n0 = blockIdx.x * 32, k0 = blockIdx.y * 32;
    int tx = threadIdx.x, ty = threadIdx.y;
    for (int i = ty; i < 32; i += 8)
        tile[i][tx] = W[(size_t)(k0 + i) * N + n0 + tx];
    __syncthreads();
    for (int i = ty; i < 32; i += 8)
        Wt[(size_t)(n0 + i) * K + k0 + tx] = f2b(tile[tx][i]);
}

__global__ __launch_bounds__(256) void f32_to_bf16_vec(
    const float* __restrict__ in, bf16_t* __restrict__ out, int n4) {
    int i = blockIdx.x * blockDim.x + threadIdx.x;
    if (i >= n4) return;
    float4 v = ((const float4*)in)[i];
    uint2 p;
    p.x = (unsigned)f2b(v.x) | ((unsigned)f2b(v.y) << 16);
    p.y = (unsigned)f2b(v.z) | ((unsigned)f2b(v.w) << 16);
    ((uint2*)out)[i] = p;
}

// ---------------- V transpose prepass ----------------
template<bool GLOBAL>
__global__ __launch_bounds__(256) void v_transpose(
    const bf16_t* __restrict__ qkv, bf16_t* __restrict__ vt, int ntok) {
    __shared__ bf16_t tile[4096];
    int tb = blockIdx.x, h = blockIdx.y, b = blockIdx.z;
    int t = threadIdx.x;
    size_t src = (size_t)b * 4096 * 3072 + (size_t)(GLOBAL ? h + 8 : h) * 64 + 2048;
    for (int u = t; u < 512; u += 256) {
        int row = u >> 3, g = u & 7;
        int lt = tb * 64 + row;
        int tok = GLOBAL ? ((lt >> 5) * 128 + 96 + (lt & 31)) : lt;
        short8 vrow = *(const short8*)(qkv + src + (size_t)tok * 3072 + g * 8);
        *(short8*)&tile[(row * 8 + (g ^ (row >> 3))) * 8] = vrow;
    }
    __syncthreads();
    for (int u = t; u < 512; u += 256) {
        int d = u >> 3, t8g = u & 7;
        short8 vcol;
#pragma unroll
        for (int j = 0; j < 8; ++j) {
            int row = t8g * 8 + j;
            vcol[j] = tile[(row * 8 + ((d >> 3) ^ (row >> 3))) * 8 + (d & 7)];
        }
        *(short8*)(vt + ((size_t)(b * 8 + h) * 64 + d) * ntok + (size_t)tb * 64 + t8g * 8) = vcol;
    }
}

// ---------------- GEMM: C[M][256-tile] = A[M][K] @ Bt[N][K]^T + bias (+res)(+relu) ---
// BM=BN=256, BK=64. 512 threads = 8 waves (2M x 4N); wave C = 128x64.
// LDS: 2 buffers x 64KB; buffer = A[ks][16 fb][512] (0..16383 shorts) +
// B[ks][16 fb][512] (16384..32767), frag-order (conflict-free ds_read_b128).
// 4 phases/K-tile as described in the file header.
__global__ __launch_bounds__(512, 2) void gemm_bt256(
    const bf16_t* __restrict__ A, const bf16_t* __restrict__ Bt,
    const float* __restrict__ bias, const float* __restrict__ bias2,
    const float* __restrict__ bias3, const float* __restrict__ resf,
    const bf16_t* __restrict__ resb, float* __restrict__ Cf,
    bf16_t* __restrict__ Cb, int N, int K, int relu) {
    __shared__ bf16_t lds[2][32768];

    int t = threadIdx.x;
    int lane = t & 63;
    int wave = t >> 6;
    int wm = (wave >> 2) * 128;
    int wn = (wave & 3) * 64;
    int m0 = blockIdx.x * 256, n0 = blockIdx.y * 256;

    // staging offsets: unit u = p*512 + t; row = (u>>6)*16 + (lane&15);
    // in-khalf col = ((lane>>4)&3)*8; LDS dst = (u&~63)*8 + lane*8 = u*8.
    size_t aoff[2], boff[2]; int sdst[2];
#pragma unroll
    for (int p = 0; p < 2; ++p) {
        int u = p * 512 + t;
        int row = ((u >> 6) << 4) + (lane & 15);
        int kk = ((u >> 4) & 3) * 8;
        aoff[p] = (size_t)(m0 + row) * K + kk;
        boff[p] = (size_t)(n0 + row) * K + kk;
        sdst[p] = (u & ~63) * 8;
    }

    // ks-half staging (2 gloads each). Order per iter: Ak0, Bk0, Ak1, Bk1.
    auto stageA = [&](int bufi, int ks, int kt) {
        int k0 = kt * 64 + ks * 32;
#pragma unroll
        for (int p = 0; p < 2; ++p)
            gload16(A + aoff[p] + k0, &lds[bufi][ks * 8192 + sdst[p]]);
    };
    auto stageB = [&](int bufi, int ks, int kt) {
        int k0 = kt * 64 + ks * 32;
#pragma unroll
        for (int p = 0; p < 2; ++p)
            gload16(Bt + boff[p] + k0, &lds[bufi][16384 + ks * 8192 + sdst[p]]);
    };

    v4f acc[8][4];
#pragma unroll
    for (int i = 0; i < 8; ++i)
#pragma unroll
        for (int j = 0; j < 4; ++j) acc[i][j] = {0.f, 0.f, 0.f, 0.f};

    int NT = K >> 6;                    // 16 or 64
    int aro = ((wave >> 2) * 8) * 512 + lane * 8;            // A frag base (ks0)
    int brd = 16384 + ((wave & 3) * 4) * 512 + lane * 8;     // B frag base (ks0)

    // prologue: tile 0 into buf 0; certify k0 halves (4 newest = Ak1,Bk1).
    stageA(0, 0, 0); stageB(0, 0, 0); stageA(0, 1, 0); stageB(0, 1, 0);
    vmwait<4>();
    __builtin_amdgcn_s_barrier();

    for (int t0 = 0; t0 < NT; ++t0) {
        int cur = t0 & 1, nxt = cur ^ 1;
        int ktn = t0 + 1 < NT ? t0 + 1 : NT - 1;   // branchless clamp (no OOB)
        short8 fa[8], fb0, fb1, fb2, fb3;

        // ---- q0: ks=0, acc[:, 0..1] ----
#pragma unroll
        for (int i = 0; i < 8; ++i)
            fa[i] = *(const short8*)&lds[cur][aro + i * 512];
        fb0 = *(const short8*)&lds[cur][brd + 0 * 512];
        fb1 = *(const short8*)&lds[cur][brd + 1 * 512];
        stageA(nxt, 0, ktn);
        __builtin_amdgcn_s_barrier();
        lgkmwait0();
        __builtin_amdgcn_sched_barrier(0);
        __builtin_amdgcn_s_setprio(1);
#pragma unroll
        for (int i = 0; i < 8; ++i) {
            acc[i][0] = __builtin_amdgcn_mfma_f32_16x16x32_bf16(fa[i], fb0, acc[i][0], 0, 0, 0);
            acc[i][1] = __builtin_amdgcn_mfma_f32_16x16x32_bf16(fa[i], fb1, acc[i][1], 0, 0, 0);
        }
        __builtin_amdgcn_s_setprio(0);
        __builtin_amdgcn_s_barrier();

        // ---- q1: ks=0, acc[:, 2..3] (A frags reused) ----
        fb2 = *(const short8*)&lds[cur][brd + 2 * 512];
        fb3 = *(const short8*)&lds[cur][brd + 3 * 512];
        stageB(nxt, 0, ktn);
        __builtin_amdgcn_s_barrier();
        lgkmwait0();
        __builtin_amdgcn_sched_barrier(0);
        __builtin_amdgcn_s_setprio(1);
#pragma unroll
        for (int i = 0; i < 8; ++i) {
            acc[i][2] = __builtin_amdgcn_mfma_f32_16x16x32_bf16(fa[i], fb2, acc[i][2], 0, 0, 0);
            acc[i][3] = __builtin_amdgcn_mfma_f32_16x16x32_bf16(fa[i], fb3, acc[i][3], 0, 0, 0);
        }
        __builtin_amdgcn_s_setprio(0);
        vmwait<4>();                    // certify Ak1(t0),Bk1(t0) for q2 reads
        __builtin_amdgcn_s_barrier();   // ...collectively, before q2 reads

        // ---- q2: ks=1, acc[:, 0..1] ----
#pragma unroll
        for (int i = 0; i < 8; ++i)
            fa[i] = *(const short8*)&lds[cur][8192 + aro + i * 512];
        fb0 = *(const short8*)&lds[cur][8192 + brd + 0 * 512];
        fb1 = *(const short8*)&lds[cur][8192 + brd + 1 * 512];
        stageA(nxt, 1, ktn);
        __builtin_amdgcn_s_barrier();
        lgkmwait0();
        __builtin_amdgcn_sched_barrier(0);
        __builtin_amdgcn_s_setprio(1);
#pragma unroll
        for (int i = 0; i < 8; ++i) {
            acc[i][0] = __builtin_amdgcn_mfma_f32_16x16x32_bf16(fa[i], fb0, acc[i][0], 0, 0, 0);
            acc[i][1] = __builtin_amdgcn_mfma_f32_16x16x32_bf16(fa[i], fb1, acc[i][1], 0, 0, 0);
        }
        __builtin_amdgcn_s_setprio(0);
        __builtin_amdgcn_s_barrier();

        // ---- q3: ks=1, acc[:, 2..3] ----
        fb2 = *(const short8*)&lds[cur][8192 + brd + 2 * 512];
        fb3 = *(const short8*)&lds[cur][8192 + brd + 3 * 512];
        stageB(nxt, 1, ktn);
        __builtin_amdgcn_s_barrier();
        lgkmwait0();
        __builtin_amdgcn_sched_barrier(0);
        __builtin_amdgcn_s_setprio(1);
#pragma unroll
        for (int i = 0; i < 8; ++i) {
            acc[i][2] = __builtin_amdgcn_mfma_f32_16x16x32_bf16(fa[i], fb2, acc[i][2], 0, 0, 0);
            acc[i][3] = __builtin_amdgcn_mfma_f32_16x16x32_bf16(fa[i], fb3, acc[i][3], 0, 0, 0);
        }
        __builtin_amdgcn_s_setprio(0);
        vmwait<4>();                    // certify Ak0(t0+1),Bk0(t0+1) for next q0
        __builtin_amdgcn_s_barrier();
    }
    vmwait<0>();                        // drain dummy last-iter stages

    // ---- epilogue ----
    int qrow = (lane >> 4) * 4;
    int c15 = lane & 15;
#pragma unroll
    for (int i = 0; i < 8; ++i) {
#pragma unroll
        for (int j = 0; j < 4; ++j) {
            int col = n0 + wn + j * 16 + c15;
            float bval;
            if (bias2) {
                int seg = col >> 10;
                const float* bp = seg == 0 ? bias : (seg == 1 ? bias2 : bias3);
                bval = bp[col & 1023];
            } else {
                bval = bias[col];
            }
#pragma unroll
            for (int r = 0; r < 4; ++r) {
                int row = m0 + wm + i * 16 + qrow + r;
                size_t idx = (size_t)row * N + col;
                float val = acc[i][j][r] + bval;
                if (resf) val += resf[idx];
                if (resb) val += b2f(resb[idx]);
                if (relu) val = fmaxf(val, 0.f);
                if (Cf) Cf[idx] = val;
                if (Cb) Cb[idx] = f2b(val);
            }
        }
    }
}

// ---------------- MFMA flash attention, pipelined (R8) ----------------
template<int NCHUNK, bool GLOBAL>
__global__ __launch_bounds__(256) void mfma_attn(
    const bf16_t* __restrict__ qkv, const bf16_t* __restrict__ vt,
    bf16_t* __restrict__ o, int head_base) {
    __shared__ bf16_t buf[32768];
    bf16_t* ldsQ = buf;
    bf16_t* ldsP = buf;
    constexpr int KB = 8192, VB = 20480;

    int qc = blockIdx.x, hh = blockIdx.y, b = blockIdx.z;
    int h = head_base + hh;
    int t = threadIdx.x, lane = t & 63, w = t >> 6;
    int quad = lane >> 4, c15 = lane & 15;
    size_t base = (size_t)b * 4096 * 3072 + (size_t)h * 64;
    const int NTOK = GLOBAL ? 1024 : 4096;
    size_t vtbase = (size_t)(b * 8 + hh) * 64 * NTOK + (GLOBAL ? 0 : (size_t)qc * 128);
    const int CADV = (GLOBAL ? 256 : 64) * 3072;   // K token advance per chunk

    size_t koff[2]; int kdst[2];
#pragma unroll
    for (int p = 0; p < 2; ++p) {
        int u = p * 256 + t;
        int s = u >> 8;
        int kl = ((u >> 6) & 3) * 16 + (lane & 15);
        int dk = s * 32 + ((lane >> 4) & 3) * 8;
        int tok0 = GLOBAL ? ((kl >> 5) * 128 + 96 + (kl & 31)) : (qc * 128 + kl);
        koff[p] = base + 1024 + (size_t)tok0 * 3072 + dk;
        kdst[p] = KB + (u & ~63) * 8;
    }
    size_t voff[2]; int vdst[2];
#pragma unroll
    for (int p = 0; p < 2; ++p) {
        int u = p * 256 + t;
        int dd = ((u >> 6) & 3) * 16 + (lane & 15);
        int kl = (u >> 8) * 32 + ((lane >> 4) & 3) * 8;
        voff[p] = vtbase + (size_t)dd * NTOK + kl;
        vdst[p] = VB + (u & ~63) * 8;
    }

    auto stage = [&](int c) {
        int q = c % 3;
        size_t ka = (size_t)c * CADV;
        size_t va = (size_t)c * 64;
#pragma unroll
        for (int p = 0; p < 2; ++p)
            gload16(qkv + koff[p] + ka, buf + kdst[p] + q * 4096);
#pragma unroll
        for (int p = 0; p < 2; ++p)
            gload16(vt + voff[p] + va, buf + vdst[p] + q * 4096);
    };

    // ---- stage Q in A-frag order ----
#pragma unroll
    for (int u = t; u < 1024; u += 256) {
        int s = u >> 9, mt = (u >> 6) & 7, qq = (u >> 4) & 3, ll = u & 15;
        int tok = qc * 128 + mt * 16 + ll;
        gload16(qkv + base + (size_t)tok * 3072 + s * 32 + qq * 8, ldsQ + (u & ~63) * 8);
    }
    stage(0);
    stage(1);
    vmwait<8>();                       // Q's 4 loads (oldest) landed, all waves
    __builtin_amdgcn_s_barrier();

    short8 fQ[2][2];
#pragma unroll
    for (int i = 0; i < 2; ++i)
#pragma unroll
        for (int s = 0; s < 2; ++s)
            fQ[i][s] = *(const short8*)(ldsQ + (s * 512 + (w * 2 + i) * 64 + lane) * 8);
    lgkmwait0();                       // fQ in regs before P region gets written
    __builtin_amdgcn_sched_barrier(0);

    v4f oacc[2][4];
    float lacc[2][4];
#pragma unroll
    for (int i = 0; i < 2; ++i)
#pragma unroll
        for (int n = 0; n < 4; ++n) oacc[i][n] = {0.f, 0.f, 0.f, 0.f};
#pragma unroll
    for (int i = 0; i < 2; ++i)
#pragma unroll
        for (int r = 0; r < 4; ++r) lacc[i][r] = 0.f;

    for (int c = 0; c < NCHUNK; ++c) {
        if (c + 1 < NCHUNK) vmwait<4>();
        else vmwait<0>();
        __builtin_amdgcn_s_barrier();
        __builtin_amdgcn_sched_barrier(0);
        if (c + 2 < NCHUNK) stage(c + 2);

        const bf16_t* Kq = buf + KB + (c % 3) * 4096;
        const bf16_t* Vq = buf + VB + (c % 3) * 4096;

        // ---- S = Q K^T ----
        v4f sacc[2][4];
#pragma unroll
        for (int i = 0; i < 2; ++i)
#pragma unroll
            for (int j = 0; j < 4; ++j) sacc[i][j] = {0.f, 0.f, 0.f, 0.f};
        __builtin_amdgcn_s_setprio(1);
#pragma unroll
        for (int s = 0; s < 2; ++s)
#pragma unroll
            for (int j = 0; j < 4; ++j) {
                short8 fK = *(const short8*)(Kq + (s * 256 + j * 64 + lane) * 8);
#pragma unroll
                for (int i = 0; i < 2; ++i)
                    sacc[i][j] = __builtin_amdgcn_mfma_f32_16x16x32_bf16(fQ[i][s], fK, sacc[i][j], 0, 0, 0);
            }
        __builtin_amdgcn_s_setprio(0);

        // ---- P = exp(S*scale); l += rowsum; P -> ldsP (A-frag, swizzled) ----
#pragma unroll
        for (int i = 0; i < 2; ++i) {
            float rs[4] = {0.f, 0.f, 0.f, 0.f};
#pragma unroll
            for (int j = 0; j < 4; ++j)
#pragma unroll
                for (int r = 0; r < 4; ++r) {
                    float p = __expf(sacc[i][j][r] * 0.125f);
                    sacc[i][j][r] = p;
                    rs[r] += p;
                }
#pragma unroll
            for (int m = 1; m < 16; m <<= 1)
#pragma unroll
                for (int r = 0; r < 4; ++r) rs[r] += __shfl_xor(rs[r], m);
#pragma unroll
            for (int r = 0; r < 4; ++r) lacc[i][r] += rs[r];
#pragma unroll
            for (int j = 0; j < 4; ++j) {
                int tt = j >> 1;
                int qq = (2 * j + (c15 >> 3)) & 3;
#pragma unroll
                for (int r = 0; r < 4; ++r) {
                    int slot = (quad * 4 + r) ^ qq;
                    int unit = (w * 2 + tt) * 128 + i * 64 + qq * 16 + slot;
                    ldsP[unit * 8 + (c15 & 7)] = f2b(sacc[i][j][r]);
                }
            }
        }

        // ---- O += P V (per-wave ldsP region: no barrier needed) ----
        __builtin_amdgcn_s_setprio(1);
#pragma unroll
        for (int tt = 0; tt < 2; ++tt) {
            short8 fP[2];
#pragma unroll
            for (int i = 0; i < 2; ++i)
                fP[i] = *(const short8*)(ldsP + ((w * 2 + tt) * 128 + i * 64
                              + quad * 16 + (c15 ^ quad)) * 8);
#pragma unroll
            for (int n = 0; n < 4; ++n) {
                short8 fV = *(const short8*)(Vq + (tt * 256 + n * 64 + lane) * 8);
#pragma unroll
                for (int i = 0; i < 2; ++i)
                    oacc[i][n] = __builtin_amdgcn_mfma_f32_16x16x32_bf16(fP[i], fV, oacc[i][n], 0, 0, 0);
            }
        }
        __builtin_amdgcn_s_setprio(0);
    }

    // ---- epilogue: O / l ----
#pragma unroll
    for (int i = 0; i < 2; ++i)
#pragma unroll
        for (int r = 0; r < 4; ++r) {
            int row = qc * 128 + (w * 2 + i) * 16 + quad * 4 + r;
            float inv = 1.f / lacc[i][r];
            bf16_t* orow = o + ((size_t)b * 4096 + row) * 1024 + h * 64;
#pragma unroll
            for (int n = 0; n < 4; ++n)
                orow[n * 16 + c15] = f2b(oacc[i][n][r] * inv);
        }
}

// ---------------- layernorm (may run in-place) ----------------
__global__ __launch_bounds__(256) void ln_kernel(
    const float* x, const float* g, const float* bta,
    float* outf, bf16_t* outb) {
    int row = blockIdx.x, t = threadIdx.x;
    const float4 vv = ((const float4*)(x + (size_t)row * 1024))[t];
    float s = vv.x + vv.y + vv.z + vv.w;
    float ss = vv.x * vv.x + vv.y * vv.y + vv.z * vv.z + vv.w * vv.w;
    for (int off = 32; off > 0; off >>= 1) {
        s += __shfl_down(s, off);
        ss += __shfl_down(ss, off);
    }
    __shared__ float red[8];
    int wave = t >> 6;
    if ((t & 63) == 0) { red[wave] = s; red[wave + 4] = ss; }
    __syncthreads();
    float ts = red[0] + red[1] + red[2] + red[3];
    float tss = red[4] + red[5] + red[6] + red[7];
    float mu = ts * (1.f / 1024.f);
    float var = tss * (1.f / 1024.f) - mu * mu;
    float rstd = rsqrtf(var + 1e-6f);
    float4 gv = ((const float4*)g)[t];
    float4 bv = ((const float4*)bta)[t];
    float4 ov;
    ov.x = (vv.x - mu) * rstd * gv.x + bv.x;
    ov.y = (vv.y - mu) * rstd * gv.y + bv.y;
    ov.z = (vv.z - mu) * rstd * gv.z + bv.z;
    ov.w = (vv.w - mu) * rstd * gv.w + bv.w;
    if (outf) ((float4*)(outf + (size_t)row * 1024))[t] = ov;
    if (outb) {
        uint2 pk;
        pk.x = (unsigned)f2b(ov.x) | ((unsigned)f2b(ov.y) << 16);
        pk.y = (unsigned)f2b(ov.z) | ((unsigned)f2b(ov.w) << 16);
        ((uint2*)(outb + (size_t)row * 1024))[t] = pk;
    }
}

// ---------------- launch ----------------
extern "C" void kernel_launch(void* const* d_in, const int* in_sizes, int n_in,
                              void* d_out, int out_size, void* d_ws, size_t ws_size,
                              hipStream_t stream) {
    const float* src = (const float*)d_in[0];
    const float* Wq = (const float*)d_in[2];  const float* bq = (const float*)d_in[3];
    const float* Wk = (const float*)d_in[4];  const float* bk = (const float*)d_in[5];
    const float* Wv = (const float*)d_in[6];  const float* bv = (const float*)d_in[7];
    const float* Wo = (const float*)d_in[8];  const float* bo = (const float*)d_in[9];
    const float* g1 = (const float*)d_in[10]; const float* be1 = (const float*)d_in[11];
    const float* W1 = (const float*)d_in[12]; const float* b1 = (const float*)d_in[13];
    const float* W2 = (const float*)d_in[14]; const float* b2 = (const float*)d_in[15];
    const float* g2 = (const float*)d_in[16]; const float* be2 = (const float*)d_in[17];
    float* out = (float*)d_out;   // also the fp32 residual stream (64 MB)
    char* ws = (char*)d_ws;
    const size_t MB = 1ull << 20;

    // layout (MB), ws >= 176 confirmed r5. Lifetimes:
    //  [0,32)    xb -> ob -> alnb          (sequential)
    //  [32,128)  qkv (96)                  (dead after attn)
    //  [128,144) vt_l  [144,148) vt_g      (dead after attn)
    //  [152,158) wqkvt (dead after QKV)  [158,160) wot (dead after out-proj)
    //  [160,168) w1t  [168,176) w2t        (live through FFN)
    //  hb = [32,160) 128MB                 (written by FFN1, after all above die)
    bf16_t* xb    = (bf16_t*)(ws + 0 * MB);
    bf16_t* ob    = (bf16_t*)(ws + 0 * MB);
    bf16_t* alnb  = (bf16_t*)(ws + 0 * MB);
    bf16_t* qkv   = (bf16_t*)(ws + 32 * MB);
    bf16_t* hb    = (bf16_t*)(ws + 32 * MB);
    bf16_t* vt_l  = (bf16_t*)(ws + 128 * MB);
    bf16_t* vt_g  = (bf16_t*)(ws + 144 * MB);
    bf16_t* wqkvt = (bf16_t*)(ws + 152 * MB);
    bf16_t* wot   = (bf16_t*)(ws + 158 * MB);
    bf16_t* w1t   = (bf16_t*)(ws + 160 * MB);
    bf16_t* w2t   = (bf16_t*)(ws + 168 * MB);

    dim3 tb(32, 8);
    transpose_convert<<<dim3(32, 32), tb, 0, stream>>>(Wq, wqkvt, 1024, 1024);
    transpose_convert<<<dim3(32, 32), tb, 0, stream>>>(Wk, wqkvt + 1024 * 1024, 1024, 1024);
    transpose_convert<<<dim3(32, 32), tb, 0, stream>>>(Wv, wqkvt + 2 * 1024 * 1024, 1024, 1024);
    transpose_convert<<<dim3(32, 32), tb, 0, stream>>>(Wo, wot, 1024, 1024);
    transpose_convert<<<dim3(128, 32), tb, 0, stream>>>(W1, w1t, 1024, 4096);
    transpose_convert<<<dim3(32, 128), tb, 0, stream>>>(W2, w2t, 4096, 1024);
    f32_to_bf16_vec<<<16384, 256, 0, stream>>>(src, xb, 4194304);

    // fused QKV: C[M][3072] = xb @ [Wq|Wk|Wv]^T, per-segment bias
    gemm_bt256<<<dim3(64, 12), 512, 0, stream>>>(xb, wqkvt, bq, bk, bv,
        nullptr, nullptr, nullptr, qkv, 3072, 1024, 0);

    // V transpose prepass
    v_transpose<false><<<dim3(64, 8, 4), 256, 0, stream>>>(qkv, vt_l, 4096);
    v_transpose<true ><<<dim3(16, 8, 4), 256, 0, stream>>>(qkv, vt_g, 1024);

    mfma_attn<2,  false><<<dim3(32, 8, 4), 256, 0, stream>>>(qkv, vt_l, ob, 0);
    mfma_attn<16, true ><<<dim3(32, 8, 4), 256, 0, stream>>>(qkv, vt_g, ob, 8);

    // out-proj + src residual -> out (fp32)
    gemm_bt256<<<dim3(64, 4), 512, 0, stream>>>(ob, wot, bo, nullptr, nullptr,
        src, nullptr, out, nullptr, 1024, 1024, 0);
    ln_kernel<<<16384, 256, 0, stream>>>(out, g1, be1, nullptr, alnb);

    // FFN unchunked: FFN1 M=16384 N=4096; FFN2 grid 64x4 = 1 full pass.
    gemm_bt256<<<dim3(64, 16), 512, 0, stream>>>(alnb, w1t, b1, nullptr, nullptr,
        nullptr, nullptr, nullptr, hb, 4096, 1024, 1);
    gemm_bt256<<<dim3(64, 4), 512, 0, stream>>>(hb, w2t, b2, nullptr, nullptr,
        nullptr, alnb, out, nullptr, 1024, 4096, 0);
    ln_kernel<<<16384, 256, 0, stream>>>(out, g2, be2, out, nullptr);

    (void)in_sizes; (void)n_in; (void)out_size; (void)ws_size;
}